// Round 4
// baseline (1148.740 us; speedup 1.0000x reference)
//
#include <hip/hip_runtime.h>
#include <hip/hip_bf16.h>

#define EPS 1e-5f

// ---------------------------------------------------------------- stats ----
__global__ __launch_bounds__(256) void stats_kernel(
    const float* __restrict__ buf, float* __restrict__ mean,
    float* __restrict__ rstd) {
  int bc = blockIdx.x;
  const float* ch = buf + (size_t)bc * 32768;
  float s = 0.f, ss = 0.f;
  for (int i = threadIdx.x; i < 32768; i += 256) {
    float v = ch[i];
    s += v; ss += v * v;
  }
  for (int o = 32; o; o >>= 1) {
    s += __shfl_down(s, o);
    ss += __shfl_down(ss, o);
  }
  __shared__ float sb[4], ssb[4];
  int wid = threadIdx.x >> 6, lane = threadIdx.x & 63;
  if (lane == 0) { sb[wid] = s; ssb[wid] = ss; }
  __syncthreads();
  if (threadIdx.x == 0) {
    float S = 0.f, SS = 0.f;
    for (int w = 0; w < 4; ++w) { S += sb[w]; SS += ssb[w]; }
    float m = S * (1.f / 32768.f);
    float var = SS * (1.f / 32768.f) - m * m;
    mean[bc] = m;
    rstd[bc] = rsqrtf(var + EPS);
  }
}

// ------------------------------------------------------------------- SE ----
__global__ void se_kernel(const float* __restrict__ mean_x,
                          const float* __restrict__ w1, const float* __restrict__ b1,
                          const float* __restrict__ w2, const float* __restrict__ b2,
                          float* __restrict__ dw) {
  __shared__ float hbuf[32];
  int t = threadIdx.x;
  if (t < 32) {
    int b = t >> 4, j = t & 15;
    float a = b1[j];
    for (int c = 0; c < 64; ++c) a += mean_x[b * 64 + c] * w1[j * 64 + c];
    hbuf[t] = a >= 0.f ? a : 0.2f * a;
  }
  __syncthreads();
  if (t < 2) {
    int b = t;
    float l0 = b2[0], l1 = b2[1];
    for (int j = 0; j < 16; ++j) {
      float h = hbuf[b * 16 + j];
      l0 += h * w2[j];
      l1 += h * w2[16 + j];
    }
    float m = fmaxf(l0, l1);
    float e0 = __expf(l0 - m), e1 = __expf(l1 - m);
    float inv = 1.f / (e0 + e1);
    dw[b * 2 + 0] = e0 * inv;
    dw[b * 2 + 1] = e1 * inv;
  }
}

// --------------------------------------------- transpose w_def -> [k][i][o]
__global__ __launch_bounds__(256) void prep_wdef(const float* __restrict__ w_def,
                                                 float* __restrict__ wTd) {
  int idx = blockIdx.x * 256 + threadIdx.x;  // 27*32*32 = 27648
  if (idx < 27648) {
    int o = idx & 31, rest = idx >> 5;
    int i = rest & 31, k = rest >> 5;
    wTd[idx] = w_def[(size_t)(o * 32 + i) * 27 + k];
  }
}

// ------------------- fused inorm+lrelu+1x1 (64->32), o-split x4 -----------
// grid 1024: blockIdx = og*256 + chunk. Weights: wave-uniform scalar loads.
__global__ __launch_bounds__(256) void first_conv_kernel(
    const float* __restrict__ x, const float* __restrict__ w,   // [32,64]
    const float* __restrict__ bias,
    const float* __restrict__ meanp, const float* __restrict__ rstdp,
    float* __restrict__ f_cp, float* __restrict__ f_pc) {
  int og = blockIdx.x >> 8;
  int chunk = blockIdx.x & 255;
  int vg = chunk * 256 + threadIdx.x;
  int b = vg >> 15, p = vg & 32767;
  float acc[8];
#pragma unroll
  for (int o = 0; o < 8; ++o) acc[o] = 0.f;
  const float* xb = x + ((size_t)b * 64) * 32768;
  const float* wg = w + (size_t)og * 8 * 64;
  for (int i = 0; i < 64; ++i) {
    float v = xb[(size_t)i * 32768 + p];
    float m = meanp[b * 64 + i], r = rstdp[b * 64 + i];
    v = (v - m) * r;
    v = v >= 0.f ? v : 0.2f * v;
#pragma unroll
    for (int o = 0; o < 8; ++o) acc[o] = fmaf(wg[o * 64 + i], v, acc[o]);
  }
  float4 v0, v1;
  float* a4 = acc;
#pragma unroll
  for (int o = 0; o < 8; ++o) {
    acc[o] += bias[og * 8 + o];
    f_cp[((size_t)b * 32 + og * 8 + o) * 32768 + p] = acc[o];
  }
  v0 = make_float4(acc[0], acc[1], acc[2], acc[3]);
  v1 = make_float4(acc[4], acc[5], acc[6], acc[7]);
  float* pc = f_pc + ((size_t)b * 32768 + p) * 32 + og * 8;
  *(float4*)pc = v0;
  *(float4*)(pc + 4) = v1;
  (void)a4;
}

// ----------------------------------------------------- tiled 3x3x3 conv ----
template <int OCG, bool REFLECT, bool NORM_IN>
__global__ __launch_bounds__(256) void conv3_kernel(
    const float* __restrict__ in,    // [B,IC,32768]
    const float* __restrict__ w,     // [OC_total,IC,27]
    const float* __restrict__ bias,  // [OC_total]
    const float* __restrict__ meanp, const float* __restrict__ rstdp,
    float* __restrict__ out,         // [B,OC_total,32768]
    int IC, int OC_total) {
  int bid = blockIdx.x;
  int tile = bid & 127;
  int rem = bid >> 7;
  int b = rem & 1;
  int og = rem >> 1;
  int tz = tile >> 4, ty = (tile >> 2) & 3, tx = tile & 3;
  int z0 = tz * 4, y0 = ty * 8, x0 = tx * 8;

  int tid = threadIdx.x;
  int lz = tid >> 6, ly = (tid >> 3) & 7, lx = tid & 7;

  __shared__ float tileS[2][720];  // [6][10][12]

  int s0 = tid, s1 = tid + 256, s2 = tid + 512;
  int g0 = 0, g1 = 0, g2 = 0;
  bool a0 = false, a1 = false, a2 = false;
  bool k0 = true, k1 = true, k2 = true;
#define DESC(S, G, A, K)                                            \
  {                                                                 \
    int hz = (S) / 120;                                             \
    int rr = (S) - hz * 120;                                        \
    int hy = rr / 12;                                               \
    int hx = rr - hy * 12;                                          \
    if ((S) < 720 && hx < 10) {                                     \
      int gz = z0 + hz - 1, gy = y0 + hy - 1, gx = x0 + hx - 1;     \
      if (REFLECT) {                                                \
        gz = gz < 0 ? -gz : (gz > 31 ? 62 - gz : gz);               \
        gy = gy < 0 ? -gy : (gy > 31 ? 62 - gy : gy);               \
        gx = gx < 0 ? -gx : (gx > 31 ? 62 - gx : gx);               \
      } else {                                                      \
        K = (unsigned)gz < 32u && (unsigned)gy < 32u &&             \
            (unsigned)gx < 32u;                                     \
        if (!(K)) { gz = 0; gy = 0; gx = 0; }                       \
      }                                                             \
      G = (gz * 32 + gy) * 32 + gx;                                 \
      A = true;                                                     \
    }                                                               \
  }
  DESC(s0, g0, a0, k0)
  DESC(s1, g1, a1, k1)
  DESC(s2, g2, a2, k2)
#undef DESC

  const float* inb = in + ((size_t)b * IC) * 32768;
  int ocbase = og * OCG;

  float acc[OCG];
#pragma unroll
  for (int o = 0; o < OCG; ++o) acc[o] = 0.f;

#define STAGE(BUF, IC2)                                             \
  {                                                                 \
    const float* ch = inb + (size_t)(IC2) * 32768;                  \
    float m = 0.f, r = 1.f;                                         \
    if (NORM_IN) {                                                  \
      m = meanp[b * IC + (IC2)];                                    \
      r = rstdp[b * IC + (IC2)];                                    \
    }                                                               \
    float v;                                                        \
    if (a0) {                                                       \
      v = k0 ? ch[g0] : 0.f;                                        \
      if (NORM_IN) { v = (v - m) * r; v = v >= 0.f ? v : 0.2f * v; }\
      tileS[BUF][s0] = v;                                           \
    }                                                               \
    if (a1) {                                                       \
      v = k1 ? ch[g1] : 0.f;                                        \
      if (NORM_IN) { v = (v - m) * r; v = v >= 0.f ? v : 0.2f * v; }\
      tileS[BUF][s1] = v;                                           \
    }                                                               \
    if (a2) {                                                       \
      v = k2 ? ch[g2] : 0.f;                                        \
      if (NORM_IN) { v = (v - m) * r; v = v >= 0.f ? v : 0.2f * v; }\
      tileS[BUF][s2] = v;                                           \
    }                                                               \
  }

  STAGE(0, 0)
  __syncthreads();

  int base = lz * 120 + ly * 12 + lx;
  for (int ic = 0; ic < IC; ++ic) {
    int cur = ic & 1;
    if (ic + 1 < IC) STAGE(cur ^ 1, ic + 1)

    float tap[27];
#pragma unroll
    for (int t = 0; t < 27; ++t) {
      int dz = t / 9, dy = (t / 3) % 3, dx = t % 3;
      tap[t] = tileS[cur][base + dz * 120 + dy * 12 + dx];
    }
    const float* wic = w + (size_t)ic * 27;
#pragma unroll
    for (int o = 0; o < OCG; ++o) {
      const float* wo = wic + (size_t)(ocbase + o) * IC * 27;  // wave-uniform
#pragma unroll
      for (int t = 0; t < 27; ++t) acc[o] = fmaf(wo[t], tap[t], acc[o]);
    }
    __syncthreads();
  }
#undef STAGE

  int p = ((z0 + lz) * 32 + (y0 + ly)) * 32 + (x0 + lx);
#pragma unroll
  for (int o = 0; o < OCG; ++o) {
    int oc = ocbase + o;
    out[((size_t)b * OC_total + oc) * 32768 + p] = acc[o] + bias[oc];
  }
}

// --------------------------------------------------------------- deform ----
// Lane<->channel layout: wave handles 8 positions (4 pairs). Gather phase:
// lane c reads channel c (coalesced 128B per corner per pos-pair). Matmul:
// lane o accumulates acc[o,pos] via 32 broadcast-shuffles of v + coalesced
// weight loads from pre-transposed wTd[k][i][o]. Writes belta in [b][p][c].
__global__ __launch_bounds__(256) void deform_kernel(
    const float* __restrict__ f_pc,  // [B,32768,32]
    const float* __restrict__ offs,  // [B,81,32768]
    const float* __restrict__ wTd,   // [27,32,32] (k,i,o)
    float* __restrict__ belta) {     // [B,32768,32]
  int tid = threadIdx.x;
  int wv = tid >> 6, lane = tid & 63;
  int half = lane >> 5, c = lane & 31;
  int wgid = blockIdx.x * 4 + wv;          // 8192 waves, 8 positions each
  int b = wgid >> 12;                      // 4096 waves per batch
  int posbase = (wgid & 4095) * 8;
  int z = posbase >> 10, y = (posbase >> 5) & 31, x0 = posbase & 31;
  const float* fb = f_pc + (((size_t)b) << 15) * 32;
  const float* ob = offs + (((size_t)b * 81) << 15);

  float acc0 = 0.f, acc1 = 0.f, acc2 = 0.f, acc3 = 0.f;

  for (int k = 0; k < 27; ++k) {
    float wreg[32];
#pragma unroll
    for (int i = 0; i < 32; ++i) wreg[i] = wTd[(k * 32 + i) * 32 + c];
    int kz = k / 9 - 1, ky = (k / 3) % 3 - 1, kx = k % 3 - 1;

#define TAPQ(Q, ACC)                                                         \
    {                                                                        \
      int pos = posbase + (Q) * 2 + half;                                    \
      float oz = ob[(size_t)(k * 3 + 0) * 32768 + pos];                      \
      float oy = ob[(size_t)(k * 3 + 1) * 32768 + pos];                      \
      float ox = ob[(size_t)(k * 3 + 2) * 32768 + pos];                      \
      float pz = (float)(z + kz) + oz;                                       \
      float py = (float)(y + ky) + oy;                                       \
      float px = (float)(x0 + (Q) * 2 + half + kx) + ox;                     \
      float fz = floorf(pz), fy = floorf(py), fxx = floorf(px);              \
      int iz0 = (int)fz, iy0 = (int)fy, ix0 = (int)fxx;                      \
      float rz = pz - fz, ry = py - fy, rx = px - fxx;                       \
      float v = 0.f;                                                         \
      _Pragma("unroll")                                                      \
      for (int corner = 0; corner < 8; ++corner) {                           \
        int dz = corner >> 2, dy = (corner >> 1) & 1, dxx = corner & 1;      \
        int iz = iz0 + dz, iy = iy0 + dy, ix = ix0 + dxx;                    \
        bool okb = (unsigned)iz < 32u && (unsigned)iy < 32u &&               \
                   (unsigned)ix < 32u;                                       \
        float wt = (dz ? rz : 1.f - rz) * (dy ? ry : 1.f - ry) *             \
                   (dxx ? rx : 1.f - rx);                                    \
        if (okb) v = fmaf(wt, fb[(size_t)((iz * 32 + iy) * 32 + ix) * 32 + c], v); \
      }                                                                      \
      _Pragma("unroll")                                                      \
      for (int i = 0; i < 32; ++i) {                                         \
        float vi = __shfl(v, i, 32);                                         \
        ACC = fmaf(wreg[i], vi, ACC);                                        \
      }                                                                      \
    }
    TAPQ(0, acc0)
    TAPQ(1, acc1)
    TAPQ(2, acc2)
    TAPQ(3, acc3)
#undef TAPQ
  }
  float* obp = belta + (((size_t)b) << 15) * 32 + (size_t)posbase * 32;
  obp[0 * 64 + lane] = acc0;
  obp[1 * 64 + lane] = acc1;
  obp[2 * 64 + lane] = acc2;
  obp[3 * 64 + lane] = acc3;
}

// ------------------- combine (pc-belta + cp-alpha) + partial stats --------
__global__ __launch_bounds__(256) void combine_kernel(
    const float* __restrict__ belta, const float* __restrict__ alpha,
    const float* __restrict__ dw, float* __restrict__ comb,
    float* __restrict__ partial) {   // [256][2]
  int blk = blockIdx.x;              // 64 bc x 4 quarters
  int bc = blk >> 2, qt = blk & 3;
  int b = bc >> 5, cch = bc & 31;
  float d0 = dw[b * 2 + 0], d1 = dw[b * 2 + 1];
  const float* bp = belta + (((size_t)b) << 15) * 32;
  const float* al = alpha + (size_t)bc * 32768;
  float* cb = comb + (size_t)bc * 32768;
  float s = 0.f, ss = 0.f;
  int i0 = qt * 8192;
  for (int i = i0 + threadIdx.x; i < i0 + 8192; i += 256) {
    float v = d0 * bp[(size_t)i * 32 + cch] + d1 * al[i];
    cb[i] = v;
    s += v; ss += v * v;
  }
  for (int o = 32; o; o >>= 1) {
    s += __shfl_down(s, o);
    ss += __shfl_down(ss, o);
  }
  __shared__ float sb[4], ssb[4];
  int wid = threadIdx.x >> 6, lane = threadIdx.x & 63;
  if (lane == 0) { sb[wid] = s; ssb[wid] = ss; }
  __syncthreads();
  if (threadIdx.x == 0) {
    float S = 0.f, SS = 0.f;
    for (int w = 0; w < 4; ++w) { S += sb[w]; SS += ssb[w]; }
    partial[blk * 2 + 0] = S;
    partial[blk * 2 + 1] = SS;
  }
}

__global__ void finalize_kernel(const float* __restrict__ partial,
                                float* __restrict__ mean, float* __restrict__ rstd) {
  int t = threadIdx.x;  // 64 = bc
  if (t < 64) {
    float S = 0.f, SS = 0.f;
    for (int q = 0; q < 4; ++q) {
      S += partial[(t * 4 + q) * 2 + 0];
      SS += partial[(t * 4 + q) * 2 + 1];
    }
    float m = S * (1.f / 32768.f);
    float var = SS * (1.f / 32768.f) - m * m;
    mean[t] = m;
    rstd[t] = rsqrtf(var + EPS);
  }
}

// ------------------- fused inorm+lrelu+1x1 (32->32), o-split x4 -----------
__global__ __launch_bounds__(256) void last_conv_kernel(
    const float* __restrict__ comb, const float* __restrict__ w,  // [32,32]
    const float* __restrict__ bias,
    const float* __restrict__ meanp, const float* __restrict__ rstdp,
    float* __restrict__ out) {
  int og = blockIdx.x >> 8;
  int chunk = blockIdx.x & 255;
  int vg = chunk * 256 + threadIdx.x;
  int b = vg >> 15, p = vg & 32767;
  float acc[8];
#pragma unroll
  for (int o = 0; o < 8; ++o) acc[o] = 0.f;
  const float* cb = comb + ((size_t)b * 32) * 32768;
  const float* wg = w + (size_t)og * 8 * 32;
  for (int i = 0; i < 32; ++i) {
    float v = cb[(size_t)i * 32768 + p];
    float m = meanp[b * 32 + i], r = rstdp[b * 32 + i];
    v = (v - m) * r;
    v = v >= 0.f ? v : 0.2f * v;
#pragma unroll
    for (int o = 0; o < 8; ++o) acc[o] = fmaf(wg[o * 32 + i], v, acc[o]);
  }
#pragma unroll
  for (int o = 0; o < 8; ++o)
    out[((size_t)b * 32 + og * 8 + o) * 32768 + p] = acc[o] + bias[og * 8 + o];
}

// ---------------------------------------------------------------- launch ---
extern "C" void kernel_launch(void* const* d_in, const int* in_sizes, int n_in,
                              void* d_out, int out_size, void* d_ws, size_t ws_size,
                              hipStream_t stream) {
  (void)in_sizes; (void)n_in; (void)out_size; (void)ws_size;
  const float* x       = (const float*)d_in[0];
  const float* w_first = (const float*)d_in[1];
  const float* b_first = (const float*)d_in[2];
  const float* w_na    = (const float*)d_in[3];
  const float* b_na    = (const float*)d_in[4];
  const float* w_last  = (const float*)d_in[5];
  const float* b_last  = (const float*)d_in[6];
  const float* w_fc1   = (const float*)d_in[7];
  const float* b_fc1   = (const float*)d_in[8];
  const float* w_fc2   = (const float*)d_in[9];
  const float* b_fc2   = (const float*)d_in[10];
  const float* w_off   = (const float*)d_in[11];
  const float* b_off   = (const float*)d_in[12];
  const float* w_def   = (const float*)d_in[13];
  float* out = (float*)d_out;

  float* ws = (float*)d_ws;
  float* mean_x  = ws + 0;        // 128
  float* rstd_x  = ws + 128;      // 128
  float* dwp     = ws + 256;      // 4
  float* mean_f  = ws + 272;      // 64
  float* rstd_f  = ws + 336;      // 64
  float* mean_c  = ws + 400;      // 64
  float* rstd_c  = ws + 464;      // 64
  float* partial = ws + 528;      // 512
  size_t off0 = 2048;
  float* wTd   = ws + off0;                       // 27,648
  float* f_cp  = ws + off0 + 28672;               // 2,097,152
  float* f_pc  = f_cp + 2097152;                  // 2,097,152
  float* offb  = f_pc + 2097152;                  // 5,308,416
  float* alpha = offb + 5308416;                  // 2,097,152
  float* belta = alpha + 2097152;                 // 2,097,152
  float* comb  = belta + 2097152;                 // 2,097,152

  // 1. stats of x (also SE global-avg-pool) + weight transpose prep
  hipLaunchKernelGGL(stats_kernel, dim3(128), dim3(256), 0, stream, x, mean_x, rstd_x);
  hipLaunchKernelGGL(prep_wdef, dim3(108), dim3(256), 0, stream, w_def, wTd);
  // 2. SE gate -> dw
  hipLaunchKernelGGL(se_kernel, dim3(1), dim3(64), 0, stream,
                     mean_x, w_fc1, b_fc1, w_fc2, b_fc2, dwp);
  // 3. f = conv1x1(lrelu(inorm(x))), two layouts, o-split x4
  hipLaunchKernelGGL(first_conv_kernel, dim3(1024), dim3(256), 0, stream,
                     x, w_first, b_first, mean_x, rstd_x, f_cp, f_pc);
  // 4. stats of f
  hipLaunchKernelGGL(stats_kernel, dim3(64), dim3(256), 0, stream, f_cp, mean_f, rstd_f);
  // 5. off = conv3x3x3(f), zero pad, 32->81
  hipLaunchKernelGGL((conv3_kernel<9, false, false>), dim3(128 * 2 * 9), dim3(256), 0, stream,
                     f_cp, w_off, b_off, nullptr, nullptr, offb, 32, 81);
  // 6. alpha = conv3x3x3(lrelu(inorm(f))), reflect pad
  hipLaunchKernelGGL((conv3_kernel<8, true, true>), dim3(128 * 2 * 4), dim3(256), 0, stream,
                     f_cp, w_na, b_na, mean_f, rstd_f, alpha, 32, 32);
  // 7. belta (deformable conv), coalesced gather, writes [b][p][c]
  hipLaunchKernelGGL(deform_kernel, dim3(2048), dim3(256), 0, stream,
                     f_pc, offb, wTd, belta);
  // 8. comb = dw0*belta + dw1*alpha, partial stats (256 blocks)
  hipLaunchKernelGGL(combine_kernel, dim3(256), dim3(256), 0, stream,
                     belta, alpha, dwp, comb, partial);
  hipLaunchKernelGGL(finalize_kernel, dim3(1), dim3(64), 0, stream,
                     partial, mean_c, rstd_c);
  // 9. out = conv1x1(lrelu(inorm(comb)))
  hipLaunchKernelGGL(last_conv_kernel, dim3(1024), dim3(256), 0, stream,
                     comb, w_last, b_last, mean_c, rstd_c, out);
}

// Round 6
// 674.556 us; speedup vs baseline: 1.7030x; 1.7030x over previous
//
#include <hip/hip_runtime.h>
#include <hip/hip_bf16.h>

#define EPS 1e-5f

// ---------------------------------------------------------------- stats ----
__global__ __launch_bounds__(256) void stats_kernel(
    const float* __restrict__ buf, float* __restrict__ mean,
    float* __restrict__ rstd) {
  int bc = blockIdx.x;
  const float* ch = buf + (size_t)bc * 32768;
  float s = 0.f, ss = 0.f;
  for (int i = threadIdx.x; i < 32768; i += 256) {
    float v = ch[i];
    s += v; ss += v * v;
  }
  for (int o = 32; o; o >>= 1) {
    s += __shfl_down(s, o);
    ss += __shfl_down(ss, o);
  }
  __shared__ float sb[4], ssb[4];
  int wid = threadIdx.x >> 6, lane = threadIdx.x & 63;
  if (lane == 0) { sb[wid] = s; ssb[wid] = ss; }
  __syncthreads();
  if (threadIdx.x == 0) {
    float S = 0.f, SS = 0.f;
    for (int w = 0; w < 4; ++w) { S += sb[w]; SS += ssb[w]; }
    float m = S * (1.f / 32768.f);
    float var = SS * (1.f / 32768.f) - m * m;
    mean[bc] = m;
    rstd[bc] = rsqrtf(var + EPS);
  }
}

// ------------------------------------------------------------------- SE ----
__global__ void se_kernel(const float* __restrict__ mean_x,
                          const float* __restrict__ w1, const float* __restrict__ b1,
                          const float* __restrict__ w2, const float* __restrict__ b2,
                          float* __restrict__ dw) {
  __shared__ float hbuf[32];
  int t = threadIdx.x;
  if (t < 32) {
    int b = t >> 4, j = t & 15;
    float a = b1[j];
    for (int c = 0; c < 64; ++c) a += mean_x[b * 64 + c] * w1[j * 64 + c];
    hbuf[t] = a >= 0.f ? a : 0.2f * a;
  }
  __syncthreads();
  if (t < 2) {
    int b = t;
    float l0 = b2[0], l1 = b2[1];
    for (int j = 0; j < 16; ++j) {
      float h = hbuf[b * 16 + j];
      l0 += h * w2[j];
      l1 += h * w2[16 + j];
    }
    float m = fmaxf(l0, l1);
    float e0 = __expf(l0 - m), e1 = __expf(l1 - m);
    float inv = 1.f / (e0 + e1);
    dw[b * 2 + 0] = e0 * inv;
    dw[b * 2 + 1] = e1 * inv;
  }
}

// --------------------------------------------- transpose w_def -> [k][i][o]
__global__ __launch_bounds__(256) void prep_wdef(const float* __restrict__ w_def,
                                                 float* __restrict__ wTd) {
  int idx = blockIdx.x * 256 + threadIdx.x;  // 27*32*32 = 27648
  if (idx < 27648) {
    int o = idx & 31, rest = idx >> 5;
    int i = rest & 31, k = rest >> 5;
    wTd[idx] = w_def[(size_t)(o * 32 + i) * 27 + k];
  }
}

// ------------------- fused inorm+lrelu+1x1 (64->32), o-split x4 -----------
__global__ __launch_bounds__(256) void first_conv_kernel(
    const float* __restrict__ x, const float* __restrict__ w,   // [32,64]
    const float* __restrict__ bias,
    const float* __restrict__ meanp, const float* __restrict__ rstdp,
    float* __restrict__ f_cp, float* __restrict__ f_pc) {
  int og = blockIdx.x >> 8;
  int chunk = blockIdx.x & 255;
  int vg = chunk * 256 + threadIdx.x;
  int b = vg >> 15, p = vg & 32767;
  float acc[8];
#pragma unroll
  for (int o = 0; o < 8; ++o) acc[o] = 0.f;
  const float* xb = x + ((size_t)b * 64) * 32768;
  const float* wg = w + (size_t)og * 8 * 64;
  for (int i = 0; i < 64; ++i) {
    float v = xb[(size_t)i * 32768 + p];
    float m = meanp[b * 64 + i], r = rstdp[b * 64 + i];
    v = (v - m) * r;
    v = v >= 0.f ? v : 0.2f * v;
#pragma unroll
    for (int o = 0; o < 8; ++o) acc[o] = fmaf(wg[o * 64 + i], v, acc[o]);
  }
#pragma unroll
  for (int o = 0; o < 8; ++o) {
    acc[o] += bias[og * 8 + o];
    f_cp[((size_t)b * 32 + og * 8 + o) * 32768 + p] = acc[o];
  }
  float4 v0 = make_float4(acc[0], acc[1], acc[2], acc[3]);
  float4 v1 = make_float4(acc[4], acc[5], acc[6], acc[7]);
  float* pc = f_pc + ((size_t)b * 32768 + p) * 32 + og * 8;
  *(float4*)pc = v0;
  *(float4*)(pc + 4) = v1;
}

// ----------------------------------------------------- tiled 3x3x3 conv ----
template <int OCG, bool REFLECT, bool NORM_IN>
__global__ __launch_bounds__(256) void conv3_kernel(
    const float* __restrict__ in,    // [B,IC,32768]
    const float* __restrict__ w,     // [OC_total,IC,27]
    const float* __restrict__ bias,  // [OC_total]
    const float* __restrict__ meanp, const float* __restrict__ rstdp,
    float* __restrict__ out,         // [B,OC_total,32768]
    int IC, int OC_total) {
  int bid = blockIdx.x;
  int tile = bid & 127;
  int rem = bid >> 7;
  int b = rem & 1;
  int og = rem >> 1;
  int tz = tile >> 4, ty = (tile >> 2) & 3, tx = tile & 3;
  int z0 = tz * 4, y0 = ty * 8, x0 = tx * 8;

  int tid = threadIdx.x;
  int lz = tid >> 6, ly = (tid >> 3) & 7, lx = tid & 7;

  __shared__ float tileS[2][720];  // [6][10][12]

  int s0 = tid, s1 = tid + 256, s2 = tid + 512;
  int g0 = 0, g1 = 0, g2 = 0;
  bool a0 = false, a1 = false, a2 = false;
  bool k0 = true, k1 = true, k2 = true;
#define DESC(S, G, A, K)                                            \
  {                                                                 \
    int hz = (S) / 120;                                             \
    int rr = (S) - hz * 120;                                        \
    int hy = rr / 12;                                               \
    int hx = rr - hy * 12;                                          \
    if ((S) < 720 && hx < 10) {                                     \
      int gz = z0 + hz - 1, gy = y0 + hy - 1, gx = x0 + hx - 1;     \
      if (REFLECT) {                                                \
        gz = gz < 0 ? -gz : (gz > 31 ? 62 - gz : gz);               \
        gy = gy < 0 ? -gy : (gy > 31 ? 62 - gy : gy);               \
        gx = gx < 0 ? -gx : (gx > 31 ? 62 - gx : gx);               \
      } else {                                                      \
        K = (unsigned)gz < 32u && (unsigned)gy < 32u &&             \
            (unsigned)gx < 32u;                                     \
        if (!(K)) { gz = 0; gy = 0; gx = 0; }                       \
      }                                                             \
      G = (gz * 32 + gy) * 32 + gx;                                 \
      A = true;                                                     \
    }                                                               \
  }
  DESC(s0, g0, a0, k0)
  DESC(s1, g1, a1, k1)
  DESC(s2, g2, a2, k2)
#undef DESC

  const float* inb = in + ((size_t)b * IC) * 32768;
  int ocbase = og * OCG;

  float acc[OCG];
#pragma unroll
  for (int o = 0; o < OCG; ++o) acc[o] = 0.f;

#define STAGE(BUF, IC2)                                             \
  {                                                                 \
    const float* ch = inb + (size_t)(IC2) * 32768;                  \
    float m = 0.f, r = 1.f;                                         \
    if (NORM_IN) {                                                  \
      m = meanp[b * IC + (IC2)];                                    \
      r = rstdp[b * IC + (IC2)];                                    \
    }                                                               \
    float v;                                                        \
    if (a0) {                                                       \
      v = k0 ? ch[g0] : 0.f;                                        \
      if (NORM_IN) { v = (v - m) * r; v = v >= 0.f ? v : 0.2f * v; }\
      tileS[BUF][s0] = v;                                           \
    }                                                               \
    if (a1) {                                                       \
      v = k1 ? ch[g1] : 0.f;                                        \
      if (NORM_IN) { v = (v - m) * r; v = v >= 0.f ? v : 0.2f * v; }\
      tileS[BUF][s1] = v;                                           \
    }                                                               \
    if (a2) {                                                       \
      v = k2 ? ch[g2] : 0.f;                                        \
      if (NORM_IN) { v = (v - m) * r; v = v >= 0.f ? v : 0.2f * v; }\
      tileS[BUF][s2] = v;                                           \
    }                                                               \
  }

  STAGE(0, 0)
  __syncthreads();

  int base = lz * 120 + ly * 12 + lx;
  for (int ic = 0; ic < IC; ++ic) {
    int cur = ic & 1;
    if (ic + 1 < IC) STAGE(cur ^ 1, ic + 1)

    float tap[27];
#pragma unroll
    for (int t = 0; t < 27; ++t) {
      int dz = t / 9, dy = (t / 3) % 3, dx = t % 3;
      tap[t] = tileS[cur][base + dz * 120 + dy * 12 + dx];
    }
    const float* wic = w + (size_t)ic * 27;
#pragma unroll
    for (int o = 0; o < OCG; ++o) {
      const float* wo = wic + (size_t)(ocbase + o) * IC * 27;  // wave-uniform
#pragma unroll
      for (int t = 0; t < 27; ++t) acc[o] = fmaf(wo[t], tap[t], acc[o]);
    }
    __syncthreads();
  }
#undef STAGE

  int p = ((z0 + lz) * 32 + (y0 + ly)) * 32 + (x0 + lx);
#pragma unroll
  for (int o = 0; o < OCG; ++o) {
    int oc = ocbase + o;
    out[((size_t)b * OC_total + oc) * 32768 + p] = acc[o] + bias[oc];
  }
}

// --------------------------------------------------------------- deform ----
// Thread-per-position, 3-way tap split. Gather: 8 corners x 8 float4 into
// v[32] (VGPRs). Matmul: wave-uniform weight loads from wTd[k][i][o]
// (compiler -> s_load + v_fmac with SGPR operand); i outer / o inner gives
// 32 independent FMAs per step. No LDS, no shuffles, no barriers.
__global__ __launch_bounds__(256) void deform_kernel(
    const float* __restrict__ f_pc,  // [B,32768,32]
    const float* __restrict__ offs,  // [B,81,32768]
    const float* __restrict__ wTd,   // [27,32,32] (k,i,o)
    float* __restrict__ part) {      // [3,B,32,32768]
  int bid = blockIdx.x;
  int kg = bid >> 8;                 // 0..2
  int tile = bid & 255;
  int vg = tile * 256 + threadIdx.x;
  int b = vg >> 15, p = vg & 32767;
  int z = p >> 10, y = (p >> 5) & 31, x = p & 31;
  const float* fb = f_pc + (((size_t)b) << 15) * 32;
  const float* ob = offs + (((size_t)b * 81) << 15);
  int kz = kg - 1;  // k = kg*9+kk, kk<9  ->  k/9 == kg

  float acc[32];
#pragma unroll
  for (int o = 0; o < 32; ++o) acc[o] = 0.f;

  for (int kk = 0; kk < 9; ++kk) {
    int k = kg * 9 + kk;
    int ky = kk / 3 - 1, kx = kk % 3 - 1;

    float oz = ob[(size_t)(k * 3 + 0) * 32768 + p];
    float oy = ob[(size_t)(k * 3 + 1) * 32768 + p];
    float ox = ob[(size_t)(k * 3 + 2) * 32768 + p];
    float pz = (float)(z + kz) + oz;
    float py = (float)(y + ky) + oy;
    float px = (float)(x + kx) + ox;
    float fz = floorf(pz), fy = floorf(py), fxx = floorf(px);
    int iz0 = (int)fz, iy0 = (int)fy, ix0 = (int)fxx;
    float rz = pz - fz, ry = py - fy, rx = px - fxx;

    float v[32];
#pragma unroll
    for (int c = 0; c < 32; ++c) v[c] = 0.f;
#pragma unroll
    for (int corner = 0; corner < 8; ++corner) {
      int dz = corner >> 2, dy = (corner >> 1) & 1, dxx = corner & 1;
      int iz = iz0 + dz, iy = iy0 + dy, ix = ix0 + dxx;
      bool okb = (unsigned)iz < 32u && (unsigned)iy < 32u && (unsigned)ix < 32u;
      float wt = (dz ? rz : 1.f - rz) * (dy ? ry : 1.f - ry) *
                 (dxx ? rx : 1.f - rx);
      if (okb) {
        const float4* src =
            (const float4*)(fb + (size_t)((iz * 32 + iy) * 32 + ix) * 32);
#pragma unroll
        for (int q = 0; q < 8; ++q) {
          float4 u = src[q];
          v[q * 4 + 0] = fmaf(wt, u.x, v[q * 4 + 0]);
          v[q * 4 + 1] = fmaf(wt, u.y, v[q * 4 + 1]);
          v[q * 4 + 2] = fmaf(wt, u.z, v[q * 4 + 2]);
          v[q * 4 + 3] = fmaf(wt, u.w, v[q * 4 + 3]);
        }
      }
    }
    const float* wk = wTd + (size_t)k * 1024;  // wave-uniform base
#pragma unroll
    for (int i = 0; i < 32; ++i) {
      float vi = v[i];
      const float* wr = wk + i * 32;
#pragma unroll
      for (int o = 0; o < 32; ++o) acc[o] = fmaf(wr[o], vi, acc[o]);
    }
  }
  float* obp = part + (((size_t)kg * 2 + b) * 32) * 32768 + p;
#pragma unroll
  for (int o = 0; o < 32; ++o) obp[(size_t)o * 32768] = acc[o];
}

// ------------------- combine (3 partials + alpha) + partial stats ---------
__global__ __launch_bounds__(256) void combine_kernel(
    const float* __restrict__ part, const float* __restrict__ alpha,
    const float* __restrict__ dw, float* __restrict__ comb,
    float* __restrict__ partial) {   // [256][2]
  int blk = blockIdx.x;              // 64 bc x 4 quarters
  int bc = blk >> 2, qt = blk & 3;
  int b = bc >> 5;
  float d0 = dw[b * 2 + 0], d1 = dw[b * 2 + 1];
  const float* p0 = part + (size_t)(bc) * 32768;
  const float* p1 = part + (size_t)(64 + bc) * 32768;
  const float* p2 = part + (size_t)(128 + bc) * 32768;
  const float* al = alpha + (size_t)bc * 32768;
  float* cb = comb + (size_t)bc * 32768;
  float s = 0.f, ss = 0.f;
  int i0 = qt * 8192;
  for (int i = i0 + threadIdx.x; i < i0 + 8192; i += 256) {
    float v = d0 * (p0[i] + p1[i] + p2[i]) + d1 * al[i];
    cb[i] = v;
    s += v; ss += v * v;
  }
  for (int o = 32; o; o >>= 1) {
    s += __shfl_down(s, o);
    ss += __shfl_down(ss, o);
  }
  __shared__ float sb[4], ssb[4];
  int wid = threadIdx.x >> 6, lane = threadIdx.x & 63;
  if (lane == 0) { sb[wid] = s; ssb[wid] = ss; }
  __syncthreads();
  if (threadIdx.x == 0) {
    float S = 0.f, SS = 0.f;
    for (int w = 0; w < 4; ++w) { S += sb[w]; SS += ssb[w]; }
    partial[blk * 2 + 0] = S;
    partial[blk * 2 + 1] = SS;
  }
}

__global__ void finalize_kernel(const float* __restrict__ partial,
                                float* __restrict__ mean, float* __restrict__ rstd) {
  int t = threadIdx.x;  // 64 = bc
  if (t < 64) {
    float S = 0.f, SS = 0.f;
    for (int q = 0; q < 4; ++q) {
      S += partial[(t * 4 + q) * 2 + 0];
      SS += partial[(t * 4 + q) * 2 + 1];
    }
    float m = S * (1.f / 32768.f);
    float var = SS * (1.f / 32768.f) - m * m;
    mean[t] = m;
    rstd[t] = rsqrtf(var + EPS);
  }
}

// ------------------- fused inorm+lrelu+1x1 (32->32), o-split x4 -----------
__global__ __launch_bounds__(256) void last_conv_kernel(
    const float* __restrict__ comb, const float* __restrict__ w,  // [32,32]
    const float* __restrict__ bias,
    const float* __restrict__ meanp, const float* __restrict__ rstdp,
    float* __restrict__ out) {
  int og = blockIdx.x >> 8;
  int chunk = blockIdx.x & 255;
  int vg = chunk * 256 + threadIdx.x;
  int b = vg >> 15, p = vg & 32767;
  float acc[8];
#pragma unroll
  for (int o = 0; o < 8; ++o) acc[o] = 0.f;
  const float* cb = comb + ((size_t)b * 32) * 32768;
  const float* wg = w + (size_t)og * 8 * 32;
  for (int i = 0; i < 32; ++i) {
    float v = cb[(size_t)i * 32768 + p];
    float m = meanp[b * 32 + i], r = rstdp[b * 32 + i];
    v = (v - m) * r;
    v = v >= 0.f ? v : 0.2f * v;
#pragma unroll
    for (int o = 0; o < 8; ++o) acc[o] = fmaf(wg[o * 32 + i], v, acc[o]);
  }
#pragma unroll
  for (int o = 0; o < 8; ++o)
    out[((size_t)b * 32 + og * 8 + o) * 32768 + p] = acc[o] + bias[og * 8 + o];
}

// ---------------------------------------------------------------- launch ---
extern "C" void kernel_launch(void* const* d_in, const int* in_sizes, int n_in,
                              void* d_out, int out_size, void* d_ws, size_t ws_size,
                              hipStream_t stream) {
  (void)in_sizes; (void)n_in; (void)out_size; (void)ws_size;
  const float* x       = (const float*)d_in[0];
  const float* w_first = (const float*)d_in[1];
  const float* b_first = (const float*)d_in[2];
  const float* w_na    = (const float*)d_in[3];
  const float* b_na    = (const float*)d_in[4];
  const float* w_last  = (const float*)d_in[5];
  const float* b_last  = (const float*)d_in[6];
  const float* w_fc1   = (const float*)d_in[7];
  const float* b_fc1   = (const float*)d_in[8];
  const float* w_fc2   = (const float*)d_in[9];
  const float* b_fc2   = (const float*)d_in[10];
  const float* w_off   = (const float*)d_in[11];
  const float* b_off   = (const float*)d_in[12];
  const float* w_def   = (const float*)d_in[13];
  float* out = (float*)d_out;

  float* ws = (float*)d_ws;
  float* mean_x  = ws + 0;        // 128
  float* rstd_x  = ws + 128;      // 128
  float* dwp     = ws + 256;      // 4
  float* mean_f  = ws + 272;      // 64
  float* rstd_f  = ws + 336;      // 64
  float* mean_c  = ws + 400;      // 64
  float* rstd_c  = ws + 464;      // 64
  float* partial = ws + 528;      // 512
  size_t off0 = 2048;
  float* wTd   = ws + off0;                       // 27,648
  float* f_cp  = ws + off0 + 28672;               // 2,097,152
  float* f_pc  = f_cp + 2097152;                  // 2,097,152
  float* offb  = f_pc + 2097152;                  // 5,308,416
  float* alpha = offb + 5308416;                  // 2,097,152
  float* part  = alpha + 2097152;                 // 6,291,456
  float* comb  = part + 6291456;                  // 2,097,152

  // 1. stats of x (also SE global-avg-pool) + weight transpose prep
  hipLaunchKernelGGL(stats_kernel, dim3(128), dim3(256), 0, stream, x, mean_x, rstd_x);
  hipLaunchKernelGGL(prep_wdef, dim3(108), dim3(256), 0, stream, w_def, wTd);
  // 2. SE gate -> dw
  hipLaunchKernelGGL(se_kernel, dim3(1), dim3(64), 0, stream,
                     mean_x, w_fc1, b_fc1, w_fc2, b_fc2, dwp);
  // 3. f = conv1x1(lrelu(inorm(x))), two layouts, o-split x4
  hipLaunchKernelGGL(first_conv_kernel, dim3(1024), dim3(256), 0, stream,
                     x, w_first, b_first, mean_x, rstd_x, f_cp, f_pc);
  // 4. stats of f
  hipLaunchKernelGGL(stats_kernel, dim3(64), dim3(256), 0, stream, f_cp, mean_f, rstd_f);
  // 5. off = conv3x3x3(f), zero pad, 32->81
  hipLaunchKernelGGL((conv3_kernel<9, false, false>), dim3(128 * 2 * 9), dim3(256), 0, stream,
                     f_cp, w_off, b_off, nullptr, nullptr, offb, 32, 81);
  // 6. alpha = conv3x3x3(lrelu(inorm(f))), reflect pad
  hipLaunchKernelGGL((conv3_kernel<8, true, true>), dim3(128 * 2 * 4), dim3(256), 0, stream,
                     f_cp, w_na, b_na, mean_f, rstd_f, alpha, 32, 32);
  // 7. belta partials (deform), SGPR-weight matmul, no LDS
  hipLaunchKernelGGL(deform_kernel, dim3(768), dim3(256), 0, stream,
                     f_pc, offb, wTd, part);
  // 8. comb = dw0*belta + dw1*alpha, partial stats
  hipLaunchKernelGGL(combine_kernel, dim3(256), dim3(256), 0, stream,
                     part, alpha, dwp, comb, partial);
  hipLaunchKernelGGL(finalize_kernel, dim3(1), dim3(64), 0, stream,
                     partial, mean_c, rstd_c);
  // 9. out = conv1x1(lrelu(inorm(comb)))
  hipLaunchKernelGGL(last_conv_kernel, dim3(1024), dim3(256), 0, stream,
                     comb, w_last, b_last, mean_c, rstd_c, out);
}